// Round 5
// baseline (86.338 us; speedup 1.0000x reference)
//
#include <hip/hip_runtime.h>
#include <stdint.h>

#define EPS 1e-8f

constexpr int NROWS = 1024;  // rows of x and of y
constexpr int K     = 256;   // feature dim
constexpr int TILE  = 32;    // 32x32 output tile per block
constexpr int KC    = 32;    // per-wave staged k-chunk
constexpr int KW    = 64;    // per-wave K span (2 chunks)

typedef __attribute__((address_space(3))) uint32_t* lds_ptr_t;
typedef const __attribute__((address_space(1))) uint32_t* glb_ptr_t;

// Round-5: TLP. Rounds 0-4 all ran 1 wave/SIMD and all landed ~40 us with
// VALUBusy ~20% regardless of schedule -> within-wave latency exposure is the
// bottleneck, not the schedule. This version: 4 waves/block, each wave owns a
// K-quarter (two KC=32 chunks in a private 8 KB buffer), 32 KB LDS/block ->
// 4 blocks/CU -> 16 waves/CU = 4 waves/SIMD. Stalls of one wave overlap with
// compute of three others.
// Carried forward (verified): global_load_lds width-16 staging; rule-#21
// swizzle (linear LDS dest + source granule g^cls + read XOR kk^(grp<<2),
// cls(row)=(row>>2)&7 -> 8 broadcast groups on 8 disjoint bank quads);
// bounded unroll (live ds_read results <= 64 VGPR).
// New: coalesced rowsum (wave-per-row, 1 KB/instr; the old lane-per-row
// pattern touched 64 cache lines per instruction); cross-wave num combine in
// LDS (reuses dead chunk buffers), 2 barriers total, none in the hot loop.
__global__ __launch_bounds__(256, 4) void ruzicka_fused(const float* __restrict__ x,
                                                        const float* __restrict__ y,
                                                        float* __restrict__ out) {
    __shared__ __align__(16) float smem[4 * 2048];  // 4 x 8 KB per-wave chunk buffers
    __shared__ __align__(16) float ssum[64];        // full-K row sums (x:0..31, y:32..63)

    const int tid  = threadIdx.x;
    const int lane = tid & 63;
    const int w    = tid >> 6;      // wave 0..3 = K-quarter owner
    const int tx   = lane & 7;      // output col group (y rows)
    const int ty   = lane >> 3;     // output row group (x rows)
    const int rowBase = blockIdx.y * TILE;
    const int colBase = blockIdx.x * TILE;

    float* chunk = &smem[w * 2048];
    const int kbase = w * KW;

    // Stage one KC=32 chunk at k-offset kc: 8 DMA instr, instr i moves rows
    // 8i..8i+7 (x-tile for i<4, y-tile for i>=4), 128B per row, linear LDS.
    const int gq = lane & 7;   // 16B granule within a 128B row
    const int r8 = lane >> 3;  // row within the 8-row group
    auto stage = [&](int kc) {
        #pragma unroll
        for (int i = 0; i < 8; ++i) {
            const int row = 8 * i + r8;            // 0..63 tile row
            const int cls = (row >> 2) & 7;
            const float* src = (i < 4) ? (x + (size_t)(rowBase + row) * K)
                                       : (y + (size_t)(colBase + row - 32) * K);
            const float* gp = src + kc + 4 * (gq ^ cls);  // pre-swizzled source
            __builtin_amdgcn_global_load_lds((glb_ptr_t)gp, (lds_ptr_t)&chunk[i * 256], 16, 0, 0);
        }
    };

    stage(kbase);  // chunk-0 DMA latency hides under the rowsum prologue

    // ---- rowsum prologue: wave w sums rows 16w..16w+15 over full K ----
    // One row per iteration: 64 lanes x float4 = the whole 1 KB row, coalesced.
    #pragma unroll
    for (int j = 0; j < 16; ++j) {
        const int row = w * 16 + j;
        const float* src = (row < 32) ? (x + (size_t)(rowBase + row) * K)
                                      : (y + (size_t)(colBase + row - 32) * K);
        const float4 v = ((const float4*)src)[lane];
        float s = (v.x + v.y) + (v.z + v.w);
        #pragma unroll
        for (int off = 32; off > 0; off >>= 1) s += __shfl_down(s, off);
        if (lane == 0) ssum[row] = s;
    }

    float num[4][4];
    #pragma unroll
    for (int r = 0; r < 4; ++r)
        #pragma unroll
        for (int c = 0; c < 4; ++c) num[r][c] = 0.0f;

    const int ka0 = ty << 2;
    const int kb0 = tx << 2;

    auto compute = [&]() {
        #pragma unroll 2
        for (int kk = 0; kk < KC; kk += 4) {
            float4 a[4], b4[4];
            #pragma unroll
            for (int r = 0; r < 4; ++r)
                a[r] = *(const float4*)&chunk[(ty * 4 + r) * KC + (kk ^ ka0)];
            #pragma unroll
            for (int c = 0; c < 4; ++c)
                b4[c] = *(const float4*)&chunk[(32 + tx * 4 + c) * KC + (kk ^ kb0)];
            #pragma unroll
            for (int r = 0; r < 4; ++r)
                #pragma unroll
                for (int c = 0; c < 4; ++c) {
                    const float m0 = fminf(a[r].x, b4[c].x);
                    const float m1 = fminf(a[r].y, b4[c].y);
                    const float m2 = fminf(a[r].z, b4[c].z);
                    const float m3 = fminf(a[r].w, b4[c].w);
                    num[r][c] += (m0 + m1) + (m2 + m3);
                }
        }
    };

    // chunk 0 (DMA long since landed; rowsum consumed everything younger)
    asm volatile("s_waitcnt vmcnt(0)" ::: "memory");
    __builtin_amdgcn_sched_barrier(0);
    compute();

    // WAR hand-off: chunk-0 ds_reads retired before the overwrite; exposed DMA
    // latency here is covered by the other 3 waves on the SIMD.
    asm volatile("s_waitcnt lgkmcnt(0)" ::: "memory");
    __builtin_amdgcn_sched_barrier(0);
    stage(kbase + KC);
    asm volatile("s_waitcnt vmcnt(0)" ::: "memory");
    __builtin_amdgcn_sched_barrier(0);
    compute();

    // ---- cross-wave combine: num_total = sum over the 4 K-quarters ----
    __syncthreads();  // all chunk reads done; chunk buffers are dead
    float (*cb)[64][20] = (float (*)[64][20])smem;  // stride 20 floats (80 B): banks spread
    #pragma unroll
    for (int r = 0; r < 4; ++r) {
        float4 t;
        t.x = num[r][0]; t.y = num[r][1]; t.z = num[r][2]; t.w = num[r][3];
        *(float4*)&cb[w][lane][r * 4] = t;
    }
    __syncthreads();

    // wave w handles output row group r=w: n = sum_p cb[p][lane][w*4..w*4+4)
    float4 n4 = *(const float4*)&cb[0][lane][w * 4];
    #pragma unroll
    for (int p = 1; p < 4; ++p) {
        const float4 q = *(const float4*)&cb[p][lane][w * 4];
        n4.x += q.x; n4.y += q.y; n4.z += q.z; n4.w += q.w;
    }

    const float  sx  = ssum[ty * 4 + w];
    const float4 sy4 = *(const float4*)&ssum[32 + tx * 4];

    float4 o;
    o.x = n4.x / (sx + sy4.x - n4.x + EPS);  // den = Sx + Sy - num + EPS
    o.y = n4.y / (sx + sy4.y - n4.y + EPS);
    o.z = n4.z / (sx + sy4.z - n4.z + EPS);
    o.w = n4.w / (sx + sy4.w - n4.w + EPS);
    *(float4*)&out[(size_t)(rowBase + ty * 4 + w) * NROWS + colBase + tx * 4] = o;
}

extern "C" void kernel_launch(void* const* d_in, const int* in_sizes, int n_in,
                              void* d_out, int out_size, void* d_ws, size_t ws_size,
                              hipStream_t stream) {
    const float* x = (const float*)d_in[0];
    const float* y = (const float*)d_in[1];
    float* out = (float*)d_out;
    (void)d_ws; (void)ws_size;

    // 32x32 tiles, 4 K-split waves per block -> 4 blocks/CU, 16 waves/CU
    ruzicka_fused<<<dim3(NROWS / TILE, NROWS / TILE), dim3(256), 0, stream>>>(x, y, out);
}